// Round 4
// baseline (52701.904 us; speedup 1.0000x reference)
//
#include <hip/hip_runtime.h>
#include <cstdint>
#include <cstddef>

// ---------------------------------------------------------------------------
// Parareal neural-ODE (MSZero_13761075216509)
// f(x) = tanh(x@W1 + b1) @ W2 ; fp32 via bf16 hi/lo 3-term split MFMA.
// R4: z-split all GEMM2 (no serial-K 128-deep chains); GEMM1 reads fp32 state
//     directly (in-kernel split) -> per-node scratch 11MB -> wide chunks;
//     32KB LDS + launch_bounds(256,3) for 3 blocks/CU; fused reduce+RK kernel.
// ---------------------------------------------------------------------------

typedef __attribute__((ext_vector_type(4))) float f32x4;
typedef __attribute__((ext_vector_type(8))) short s16x8;

#define DEV __device__ __forceinline__

DEV unsigned short f2bf(float x) {
  union { float f; uint32_t u; } v; v.f = x;
  uint32_t r = v.u + 0x7FFFu + ((v.u >> 16) & 1u);   // RNE
  return (unsigned short)(r >> 16);
}
DEV float bf2f(unsigned short h) {
  union { uint32_t u; float f; } v; v.u = ((uint32_t)h) << 16; return v.f;
}
DEV void split2(float x, unsigned short &h, unsigned short &l) {
  h = f2bf(x);
  l = f2bf(x - bf2f(h));
}
DEV float fast_tanh(float z) {
  return 1.f - 2.f / (__expf(2.f * z) + 1.f);
}
DEV void gload16(const unsigned short* g, unsigned short* l) {
  __builtin_amdgcn_global_load_lds(
      (const __attribute__((address_space(1))) void*)g,
      (__attribute__((address_space(3))) void*)l, 16, 0, 0);
}

// ---------------------------------------------------------------------------
// GEMM: C[M,N] = A[M,K]*B[K,N].
// B pre-transposed hi/lo bf16 [N][K] (gload_lds staged).
// A: STAGEA=1 -> fp32 [M][K], reg-staged + split in kernel.
//    STAGEA=0 -> pre-split hi/lo bf16 [M][K], gload_lds staged.
// 3-term split: Ah*Bh + Ah*Bl + Al*Bh, fp32 MFMA accumulate.
// EPI=1: v = tanh(acc + bias[col]) -> Oh/Ol bf16 [M][N]
// EPI=2: fp32 partial at Part + blockIdx.z*M*N (split-K over z)
// Tiles 128x128, BK=32, single-buffered 32KB LDS, m97 2-barrier schedule.
// ---------------------------------------------------------------------------
template<int EPI, int STAGEA>
__global__ __launch_bounds__(256, 3) void gemm_k(
    const float* __restrict__ Asrc,
    const unsigned short* __restrict__ Ah, const unsigned short* __restrict__ Al,
    const unsigned short* __restrict__ Bh, const unsigned short* __restrict__ Bl,
    const float* __restrict__ bias,
    float* __restrict__ Part,
    unsigned short* __restrict__ Oh, unsigned short* __restrict__ Ol,
    int M, int N, int K, int KS)
{
  __shared__ unsigned short sAh[128 * 32];
  __shared__ unsigned short sAl[128 * 32];
  __shared__ unsigned short sBh[128 * 32];
  __shared__ unsigned short sBl[128 * 32];
  const int tid = threadIdx.x;
  const int w = tid >> 6, l = tid & 63;
  const int m0 = blockIdx.y * 128, n0 = blockIdx.x * 128;
  const size_t kbeg = (size_t)blockIdx.z * (size_t)KS;
  const int wm = (w >> 1) * 64, wn = (w & 1) * 64;

  f32x4 acc[4][4];
#pragma unroll
  for (int a = 0; a < 4; ++a)
#pragma unroll
    for (int b = 0; b < 4; ++b) acc[a][b] = (f32x4){0.f, 0.f, 0.f, 0.f};

  // gload staging geometry (per 8KB half-tile [128 rows][32 k] bf16):
  // thread covers bytes [tid*16,+16) and [tid*16+4096,+16)
  const int o0 = tid * 16;
  const int r0 = o0 >> 6;              // row 0..63
  const int c0 = (o0 & 63) >> 1;       // k-elem 0/8/16/24
  const size_t strideH = (size_t)64 * (size_t)K;
  const unsigned short* pbh = Bh + (size_t)(n0 + r0) * K + kbeg + c0;
  const unsigned short* pbl = Bl + (size_t)(n0 + r0) * K + kbeg + c0;
  const unsigned short* pah = nullptr; const unsigned short* pal = nullptr;
  if (STAGEA == 0) {
    pah = Ah + (size_t)(m0 + r0) * K + kbeg + c0;
    pal = Al + (size_t)(m0 + r0) * K + kbeg + c0;
  }
  const int db = w * 512;              // wave-uniform LDS dest (ushort idx)

  // STAGEA=1 geometry: thread covers A row (tid>>1), k-half (tid&1)*16
  const int ar = tid >> 1;
  const int akh = (tid & 1) * 16;
  const float* pax = nullptr;
  if (STAGEA == 1) pax = Asrc + (size_t)(m0 + ar) * K + kbeg + akh;
  const int awo = ar * 32 + akh;       // LDS ushort offset of thread's 16 elems

  const int nk = KS >> 5;
  const int aoff = (l & 15) * 32 + (l >> 4) * 8;   // frag read offset

  for (int kt = 0; kt < nk; ++kt) {
    const size_t ko = (size_t)kt * 32;
    // ---- stage A ----
    if (STAGEA == 1) {
      f32x4 v0 = *(const f32x4*)(pax + ko);
      f32x4 v1 = *(const f32x4*)(pax + ko + 4);
      f32x4 v2 = *(const f32x4*)(pax + ko + 8);
      f32x4 v3 = *(const f32x4*)(pax + ko + 12);
      s16x8 h0, h1, l0, l1;
#pragma unroll
      for (int j = 0; j < 4; ++j) {
        unsigned short hh, ll;
        split2(v0[j], hh, ll); h0[j] = (short)hh; l0[j] = (short)ll;
        split2(v1[j], hh, ll); h0[4 + j] = (short)hh; l0[4 + j] = (short)ll;
        split2(v2[j], hh, ll); h1[j] = (short)hh; l1[j] = (short)ll;
        split2(v3[j], hh, ll); h1[4 + j] = (short)hh; l1[4 + j] = (short)ll;
      }
      *(s16x8*)&sAh[awo] = h0; *(s16x8*)&sAh[awo + 8] = h1;
      *(s16x8*)&sAl[awo] = l0; *(s16x8*)&sAl[awo + 8] = l1;
    } else {
      gload16(pah + ko, &sAh[db]); gload16(pah + ko + strideH, &sAh[db + 2048]);
      gload16(pal + ko, &sAl[db]); gload16(pal + ko + strideH, &sAl[db + 2048]);
    }
    // ---- stage B ----
    gload16(pbh + ko, &sBh[db]); gload16(pbh + ko + strideH, &sBh[db + 2048]);
    gload16(pbl + ko, &sBl[db]); gload16(pbl + ko + strideH, &sBl[db + 2048]);
    __syncthreads();

    s16x8 bfh[4], bfl[4];
#pragma unroll
    for (int ni = 0; ni < 4; ++ni) {
      bfh[ni] = *(const s16x8*)&sBh[(wn + ni * 16) * 32 + aoff];
      bfl[ni] = *(const s16x8*)&sBl[(wn + ni * 16) * 32 + aoff];
    }
#pragma unroll
    for (int mi = 0; mi < 4; ++mi) {
      const s16x8 afh = *(const s16x8*)&sAh[(wm + mi * 16) * 32 + aoff];
      const s16x8 afl = *(const s16x8*)&sAl[(wm + mi * 16) * 32 + aoff];
#pragma unroll
      for (int ni = 0; ni < 4; ++ni) {
        acc[mi][ni] = __builtin_amdgcn_mfma_f32_16x16x32_bf16(afh, bfh[ni], acc[mi][ni], 0, 0, 0);
        acc[mi][ni] = __builtin_amdgcn_mfma_f32_16x16x32_bf16(afh, bfl[ni], acc[mi][ni], 0, 0, 0);
        acc[mi][ni] = __builtin_amdgcn_mfma_f32_16x16x32_bf16(afl, bfh[ni], acc[mi][ni], 0, 0, 0);
      }
    }
    __syncthreads();
  }

  // epilogue: row = wm+mi*16+(l>>4)*4+j, col = wn+ni*16+(l&15)
  const int colb = n0 + wn + (l & 15);
  const int rowb = m0 + wm + (l >> 4) * 4;

  if (EPI == 1) {
#pragma unroll
    for (int mi = 0; mi < 4; ++mi)
#pragma unroll
      for (int ni = 0; ni < 4; ++ni) {
        const int col = colb + ni * 16;
        const float bc = bias[col];
#pragma unroll
        for (int j = 0; j < 4; ++j) {
          const size_t idx = (size_t)(rowb + mi * 16 + j) * N + col;
          const float v = fast_tanh(acc[mi][ni][j] + bc);
          unsigned short hh, ll; split2(v, hh, ll);
          Oh[idx] = hh; Ol[idx] = ll;
        }
      }
  } else {
    float* dst = Part + (size_t)blockIdx.z * (size_t)M * N;
#pragma unroll
    for (int mi = 0; mi < 4; ++mi)
#pragma unroll
      for (int ni = 0; ni < 4; ++ni) {
        const int col = colb + ni * 16;
#pragma unroll
        for (int j = 0; j < 4; ++j)
          dst[(size_t)(rowb + mi * 16 + j) * N + col] = acc[mi][ni][j];
      }
  }
}

// ---------------------------------------------------------------------------
// fused split-K reduce + state update. F = sum_z Part[z].
// mode 0: X = X + sdt*F (+Dv) (+Bout=X)           (Euler / seq correction)
// mode 1: ACC = X + (sdt/6)F ; XT = X + (sdt/2)F  (RK k1)
// mode 2: ACC += (sdt/3)F    ; XT = X + (sdt/2)F  (RK k2)
// mode 3: ACC += (sdt/3)F    ; XT = X + sdt*F     (RK k3)
// mode 4: X = ACC + (sdt/6)F                      (RK k4)
// ---------------------------------------------------------------------------
__global__ void reduce_upd_k(const float* __restrict__ Part, int SPL, int MN4,
    const float* __restrict__ tspan, int mode,
    float* __restrict__ X, float* __restrict__ ACC, float* __restrict__ XT,
    const float* __restrict__ Dv, float* __restrict__ Bout)
{
  const int i = blockIdx.x * blockDim.x + threadIdx.x;
  if (i >= MN4) return;
  const float sdt = (tspan[1] - tspan[0]) * (1.0f / 7.0f);
  const size_t MN = (size_t)MN4 * 4;
  const size_t o = 4 * (size_t)i;
  f32x4 F = *(const f32x4*)(Part + o);
  for (int z = 1; z < SPL; ++z) F += *(const f32x4*)(Part + (size_t)z * MN + o);

  if (mode == 0) {
    f32x4 v = *(const f32x4*)(X + o) + sdt * F;
    if (Dv) v += *(const f32x4*)(Dv + o);
    *(f32x4*)(X + o) = v;
    if (Bout) *(f32x4*)(Bout + o) = v;
  } else if (mode == 1) {
    const f32x4 x = *(const f32x4*)(X + o);
    *(f32x4*)(ACC + o) = x + (sdt * (1.f / 6.f)) * F;
    *(f32x4*)(XT + o) = x + (sdt * 0.5f) * F;
  } else if (mode == 2) {
    const f32x4 x = *(const f32x4*)(X + o);
    *(f32x4*)(ACC + o) = *(const f32x4*)(ACC + o) + (sdt * (1.f / 3.f)) * F;
    *(f32x4*)(XT + o) = x + (sdt * 0.5f) * F;
  } else if (mode == 3) {
    const f32x4 x = *(const f32x4*)(X + o);
    *(f32x4*)(ACC + o) = *(const f32x4*)(ACC + o) + (sdt * (1.f / 3.f)) * F;
    *(f32x4*)(XT + o) = x + sdt * F;
  } else {
    *(f32x4*)(X + o) = *(const f32x4*)(ACC + o) + (sdt * (1.f / 6.f)) * F;
  }
}

// ---------------------------------------------------------------------------
// dst = A - B (dst may alias B)
// ---------------------------------------------------------------------------
__global__ void sub_k(float* __restrict__ dst, const float* __restrict__ A,
                      const float* __restrict__ B, int n4)
{
  for (int i = blockIdx.x * blockDim.x + threadIdx.x; i < n4;
       i += gridDim.x * blockDim.x) {
    const size_t o = 4 * (size_t)i;
    const f32x4 v = *(const f32x4*)(A + o) - *(const f32x4*)(B + o);
    *(f32x4*)(dst + o) = v;
  }
}

// ---------------------------------------------------------------------------
// W [K][N] fp32 -> Th/Tl [N][K] bf16 hi/lo (once per launch)
// ---------------------------------------------------------------------------
__global__ void transpose_split_k(const float* __restrict__ W,
                                  unsigned short* __restrict__ Th,
                                  unsigned short* __restrict__ Tl,
                                  int K, int N)
{
  __shared__ float t[32][33];
  const int tx = threadIdx.x & 31, ty = threadIdx.x >> 5;
  const int n0 = blockIdx.x * 32, k0 = blockIdx.y * 32;
#pragma unroll
  for (int r = 0; r < 4; ++r) {
    const int row = ty + r * 8;
    t[row][tx] = W[(size_t)(k0 + row) * N + n0 + tx];
  }
  __syncthreads();
#pragma unroll
  for (int r = 0; r < 4; ++r) {
    const int row = ty + r * 8;
    const float v = t[tx][row];
    unsigned short hh, ll; split2(v, hh, ll);
    const size_t idx = (size_t)(n0 + row) * K + k0 + tx;
    Th[idx] = hh; Tl[idx] = ll;
  }
}

// ---------------------------------------------------------------------------
extern "C" void kernel_launch(void* const* d_in, const int* in_sizes, int n_in,
                              void* d_out, int out_size, void* d_ws, size_t ws_size,
                              hipStream_t stream)
{
  const float* Bin   = (const float*)d_in[0];
  const float* tspan = (const float*)d_in[1];
  const float* W1    = (const float*)d_in[2];
  const float* b1    = (const float*)d_in[3];
  const float* W2    = (const float*)d_in[4];

  const int n = in_sizes[1];                 // 16
  const int h = in_sizes[3];                 // 4096
  const int d = in_sizes[2] / h;             // 1024
  const int batch = in_sizes[0] / (n * d);   // 256
  const int S = 7;                           // fine_steps-1
  const int MAXIT = 2;
  const size_t NB = (size_t)batch * d;       // 262144 elems = 1 MiB fp32
  const int SPL_V = 4;

  float* Bw = (float*)d_out;

  uint8_t* wsb = (uint8_t*)d_ws;
  size_t off = 0;
  auto carve = [&](size_t bytes) -> void* {
    off = (off + 255) & ~(size_t)255;
    void* p = wsb + off; off += bytes; return p;
  };

  const size_t WH = (size_t)d * h;
  unsigned short* W1Th = (unsigned short*)carve(WH * 2);
  unsigned short* W1Tl = (unsigned short*)carve(WH * 2);
  unsigned short* W2Th = (unsigned short*)carve(WH * 2);
  unsigned short* W2Tl = (unsigned short*)carve(WH * 2);
  float* Dbuf = (float*)carve((size_t)(n - 1) * NB * 4);

  // chunk width: per node = Xf(4) + ACC(4) + XT(4) + Y(2+2 @h) + Part(SPL_V*4)
  const size_t per_node = NB * 4 * 3 + (size_t)batch * h * 4 + NB * 4 * SPL_V;
  int c;
  {
    size_t remb = ws_size > off + (1u << 20) ? ws_size - off - (1u << 20) : 0;
    c = (int)(remb / per_node);
    if (c < 1) c = 1;
    if (c > n - 1) c = n - 1;
  }
  const size_t CE = (size_t)c * NB;
  float*          Xf  = (float*)carve(CE * 4);
  float*          ACC = (float*)carve(CE * 4);
  float*          XT  = (float*)carve(CE * 4);
  unsigned short* Yh  = (unsigned short*)carve((size_t)c * batch * h * 2);
  unsigned short* Yl  = (unsigned short*)carve((size_t)c * batch * h * 2);
  float*          Part = (float*)carve(CE * 4 * SPL_V);
  const int SPL_S = (SPL_V * c >= 8) ? 8 : 4;   // seq split (Part capacity)

  auto rgrid = [](int n4) -> int { return (n4 + 255) / 256; };

  // g1: Y = tanh(Xsrc@W1 + b1), Xsrc fp32 [M][d]
  auto g1 = [&](const float* Xsrc, int M) {
    gemm_k<1, 1><<<dim3(h / 128, M / 128, 1), 256, 0, stream>>>(
        Xsrc, nullptr, nullptr, W1Th, W1Tl, b1, nullptr, Yh, Yl, M, h, d, d);
  };
  // g2: Part[z] = Y@W2 partials (split-K)
  auto g2 = [&](int M, int spl) {
    gemm_k<2, 0><<<dim3(d / 128, M / 128, spl), 256, 0, stream>>>(
        nullptr, Yh, Yl, W2Th, W2Tl, nullptr, Part, nullptr, nullptr,
        M, d, h, h / spl);
  };
  auto red = [&](int M, int spl, int mode, float* X, const float* Dv, float* Bout) {
    const int mn4 = (int)((size_t)M * d / 4);
    reduce_upd_k<<<rgrid(mn4), 256, 0, stream>>>(
        Part, spl, mn4, tspan, mode, X, ACC, XT, Dv, Bout);
  };

  // ---- prep ---------------------------------------------------------------
  hipMemcpyAsync(Bw, Bin, (size_t)n * NB * 4, hipMemcpyDeviceToDevice, stream);
  transpose_split_k<<<dim3(h / 32, d / 32), 256, 0, stream>>>(W1, W1Th, W1Tl, d, h);
  transpose_split_k<<<dim3(d / 32, h / 32), 256, 0, stream>>>(W2, W2Th, W2Tl, h, d);

  // ---- Parareal outer loop ------------------------------------------------
  for (int i = 1; i <= MAXIT + 1; ++i) {
    const int rem = n - i;

    for (int base = 0; base < rem; base += c) {
      const int cc = (rem - base) < c ? (rem - base) : c;
      const int M = cc * batch;
      const size_t bytes = (size_t)M * d * 4;
      const float* src = Bw + (size_t)(i - 1 + base) * NB;
      float* Dslot = Dbuf + (size_t)base * NB;

      // coarse Euler sweep, state lives in Dslot
      hipMemcpyAsync(Dslot, src, bytes, hipMemcpyDeviceToDevice, stream);
      for (int s = 0; s < S; ++s) {
        g1(Dslot, M); g2(M, SPL_V);
        red(M, SPL_V, 0, Dslot, nullptr, nullptr);
      }
      // fine RK4 sweep, state in Xf
      hipMemcpyAsync(Xf, src, bytes, hipMemcpyDeviceToDevice, stream);
      for (int s = 0; s < S; ++s) {
        g1(Xf, M); g2(M, SPL_V); red(M, SPL_V, 1, Xf, nullptr, nullptr);  // k1
        g1(XT, M); g2(M, SPL_V); red(M, SPL_V, 2, Xf, nullptr, nullptr);  // k2
        g1(XT, M); g2(M, SPL_V); red(M, SPL_V, 3, Xf, nullptr, nullptr);  // k3
        g1(XT, M); g2(M, SPL_V); red(M, SPL_V, 4, Xf, nullptr, nullptr);  // k4
      }
      // D = fine - coarse
      sub_k<<<rgrid((int)(bytes / 16)), 256, 0, stream>>>(Dslot, Xf, Dslot, (int)(bytes / 16));
    }

    // sequential Parareal correction
    hipMemcpyAsync(Xf, Bw + (size_t)(i - 1) * NB, NB * 4, hipMemcpyDeviceToDevice, stream);
    for (int m = 0; m < rem; ++m) {
      for (int s = 0; s < S; ++s) {
        g1(Xf, batch);
        g2(batch, SPL_S);
        const bool last = (s == S - 1);
        red(batch, SPL_S, 0, Xf,
            last ? Dbuf + (size_t)m * NB : nullptr,
            last ? Bw + (size_t)(i + m) * NB : nullptr);
      }
    }
  }
}

// Round 5
// 37301.920 us; speedup vs baseline: 1.4128x; 1.4128x over previous
//
#include <hip/hip_runtime.h>
#include <cstdint>
#include <cstddef>

// ---------------------------------------------------------------------------
// Parareal neural-ODE (MSZero_13761075216509)
// f(x) = tanh(x@W1 + b1) @ W2 ; fp32 via bf16 hi/lo 3-term split MFMA.
// R5: sequential phase rebuilt for full-chip occupancy: both GEMMs z-split
//     (256 WGs, 8 K-steps each) + fused reduce kernels. Vectorized phase
//     and GEMM template identical to R3 (known-good).
// ---------------------------------------------------------------------------

typedef __attribute__((ext_vector_type(4))) float f32x4;
typedef __attribute__((ext_vector_type(8))) short s16x8;
typedef __attribute__((ext_vector_type(4))) unsigned short u16x4;

#define DEV __device__ __forceinline__

DEV unsigned short f2bf(float x) {
  union { float f; uint32_t u; } v; v.f = x;
  uint32_t r = v.u + 0x7FFFu + ((v.u >> 16) & 1u);   // RNE
  return (unsigned short)(r >> 16);
}
DEV float bf2f(unsigned short h) {
  union { uint32_t u; float f; } v; v.u = ((uint32_t)h) << 16; return v.f;
}
DEV void split2(float x, unsigned short &h, unsigned short &l) {
  h = f2bf(x);
  l = f2bf(x - bf2f(h));
}
DEV float fast_tanh(float z) {
  return 1.f - 2.f / (__expf(2.f * z) + 1.f);
}
DEV void gload16(const unsigned short* g, unsigned short* l) {
  __builtin_amdgcn_global_load_lds(
      (const __attribute__((address_space(1))) void*)g,
      (__attribute__((address_space(3))) void*)l, 16, 0, 0);
}

// ---------------------------------------------------------------------------
// GEMM: C[M,N] = A[M,K]*B[K,N]; A hi/lo bf16 [M][K], B pre-transposed hi/lo
// bf16 [N][K]. 3-term split: Ah*Bh + Ah*Bl + Al*Bh, fp32 MFMA accumulate.
// LDS tile: [128 rows][8 slots x 16B] per operand, phys slot = src ^ (row&7)
// (conflict-free b128 reads); double-buffered, prefetch-issue-early.
// EPI=1: v=tanh(acc+bias[col]) -> Oh/Ol bf16
// EPI=2: fp32 partial at Part + blockIdx.z*M*N (split-K)
// EPI=3: rk-update: a=(add?ACC:X)+a1*sdt*acc -> ACC ; xt=X+a2*sdt*acc -> Oh/Ol
// EPI=4: axpy-update: v=Xin+(a1+a2*sdt)*acc -> Xout fp32 + Oh/Ol split
// ---------------------------------------------------------------------------
template<int EPI>
__global__ __launch_bounds__(256, 2) void gemm_k(
    const unsigned short* __restrict__ Ah, const unsigned short* __restrict__ Al,
    const unsigned short* __restrict__ Bh, const unsigned short* __restrict__ Bl,
    const float* __restrict__ bias,
    float* __restrict__ Part,
    unsigned short* __restrict__ Oh, unsigned short* __restrict__ Ol,
    const float* __restrict__ Xin,
    float* __restrict__ ACCb,
    float* __restrict__ Xout,
    const float* __restrict__ tspan,
    float a1, float a2, int accAdd,
    int M, int N, int K, int KS)
{
  __shared__ unsigned short sA[2][128 * 64];
  __shared__ unsigned short sB[2][128 * 64];
  const int tid = threadIdx.x;
  const int w = tid >> 6, l = tid & 63;
  const int m0 = blockIdx.y * 128, n0 = blockIdx.x * 128;
  const size_t kbeg = (size_t)blockIdx.z * (size_t)KS;
  const int wm = (w >> 1) * 64, wn = (w & 1) * 64;

  f32x4 acc[4][4];
#pragma unroll
  for (int a = 0; a < 4; ++a)
#pragma unroll
    for (int b = 0; b < 4; ++b) acc[a][b] = (f32x4){0.f, 0.f, 0.f, 0.f};

  // staging geometry: call j of wave w writes bytes [w*1024 + j*4096 + lane*16)
  // -> row j*32 + w*8 + (l>>3), phys slot l&7; phys slot holds src ^ (row&7)
  const int rsub = w * 8 + (l >> 3);
  const int ssrc = (l & 7) ^ (l >> 3);
  const int shalf = ssrc >> 2;
  const int schunk = ssrc & 3;
  const unsigned short* gA = (shalf ? Al : Ah) + (size_t)(m0 + rsub) * K + kbeg + schunk * 8;
  const unsigned short* gB = (shalf ? Bl : Bh) + (size_t)(n0 + rsub) * K + kbeg + schunk * 8;
  const size_t gstep = (size_t)32 * (size_t)K;
  const int db = w * 512;

  // fragment-read: A[R0+(l&15)][k=(l>>4)*8..]; phys slot = (h*4+(l>>4))^(l&7)
  const int arow = (l & 15);
  const int slotH = ((l >> 4)) ^ (l & 7);
  const int slotL = (4 + (l >> 4)) ^ (l & 7);

  const int nk = KS >> 5;

  auto STAGE = [&](int buf, int kt) {
    const size_t ko = (size_t)kt * 32;
    unsigned short* da = &sA[buf][db];
    unsigned short* dbp = &sB[buf][db];
#pragma unroll
    for (int j = 0; j < 4; ++j) {
      gload16(gA + ko + (size_t)j * gstep, da + j * 2048);
      gload16(gB + ko + (size_t)j * gstep, dbp + j * 2048);
    }
  };

  STAGE(0, 0);
  __syncthreads();
  int cur = 0;

  for (int kt = 0; kt < nk; ++kt) {
    if (kt + 1 < nk) STAGE(cur ^ 1, kt + 1);
    const unsigned short* pa = &sA[cur][0];
    const unsigned short* pb = &sB[cur][0];
    s16x8 afh[4], afl[4], bfh[4], bfl[4];
#pragma unroll
    for (int mi = 0; mi < 4; ++mi) {
      const int rb = (wm + mi * 16 + arow) * 64;
      afh[mi] = *(const s16x8*)&pa[rb + slotH * 8];
      afl[mi] = *(const s16x8*)&pa[rb + slotL * 8];
    }
#pragma unroll
    for (int ni = 0; ni < 4; ++ni) {
      const int rb = (wn + ni * 16 + arow) * 64;
      bfh[ni] = *(const s16x8*)&pb[rb + slotH * 8];
      bfl[ni] = *(const s16x8*)&pb[rb + slotL * 8];
    }
#pragma unroll
    for (int mi = 0; mi < 4; ++mi)
#pragma unroll
      for (int ni = 0; ni < 4; ++ni) {
        acc[mi][ni] = __builtin_amdgcn_mfma_f32_16x16x32_bf16(afh[mi], bfh[ni], acc[mi][ni], 0, 0, 0);
        acc[mi][ni] = __builtin_amdgcn_mfma_f32_16x16x32_bf16(afh[mi], bfl[ni], acc[mi][ni], 0, 0, 0);
        acc[mi][ni] = __builtin_amdgcn_mfma_f32_16x16x32_bf16(afl[mi], bfh[ni], acc[mi][ni], 0, 0, 0);
      }
    __syncthreads();
    cur ^= 1;
  }

  // epilogue: row = wm+mi*16+(l>>4)*4+j, col = wn+ni*16+(l&15)
  const int colb = n0 + wn + (l & 15);
  const int rowb = m0 + wm + (l >> 4) * 4;
  const float sdt = (EPI >= 3) ? (tspan[1] - tspan[0]) * (1.0f / 7.0f) : 0.f;

  if (EPI == 1) {
#pragma unroll
    for (int mi = 0; mi < 4; ++mi)
#pragma unroll
      for (int ni = 0; ni < 4; ++ni) {
        const int col = colb + ni * 16;
        const float bc = bias[col];
#pragma unroll
        for (int j = 0; j < 4; ++j) {
          const size_t idx = (size_t)(rowb + mi * 16 + j) * N + col;
          const float v = fast_tanh(acc[mi][ni][j] + bc);
          unsigned short hh, ll; split2(v, hh, ll);
          Oh[idx] = hh; Ol[idx] = ll;
        }
      }
  } else if (EPI == 2) {
    float* dst = Part + (size_t)blockIdx.z * (size_t)M * N;
#pragma unroll
    for (int mi = 0; mi < 4; ++mi)
#pragma unroll
      for (int ni = 0; ni < 4; ++ni) {
        const int col = colb + ni * 16;
#pragma unroll
        for (int j = 0; j < 4; ++j)
          dst[(size_t)(rowb + mi * 16 + j) * N + col] = acc[mi][ni][j];
      }
  } else if (EPI == 3) {
    const float c1 = a1 * sdt, c2 = a2 * sdt;
#pragma unroll
    for (int mi = 0; mi < 4; ++mi)
#pragma unroll
      for (int ni = 0; ni < 4; ++ni) {
        const int col = colb + ni * 16;
#pragma unroll
        for (int j = 0; j < 4; ++j) {
          const size_t idx = (size_t)(rowb + mi * 16 + j) * N + col;
          const float f = acc[mi][ni][j];
          const float x = Xin[idx];
          const float a = (accAdd ? ACCb[idx] : x) + c1 * f;
          ACCb[idx] = a;
          const float xt = x + c2 * f;
          unsigned short hh, ll; split2(xt, hh, ll);
          Oh[idx] = hh; Ol[idx] = ll;
        }
      }
  } else {  // EPI == 4
    const float coef = a1 + a2 * sdt;
#pragma unroll
    for (int mi = 0; mi < 4; ++mi)
#pragma unroll
      for (int ni = 0; ni < 4; ++ni) {
        const int col = colb + ni * 16;
#pragma unroll
        for (int j = 0; j < 4; ++j) {
          const size_t idx = (size_t)(rowb + mi * 16 + j) * N + col;
          const float v = Xin[idx] + coef * acc[mi][ni][j];
          Xout[idx] = v;
          unsigned short hh, ll; split2(v, hh, ll);
          Oh[idx] = hh; Ol[idx] = ll;
        }
      }
  }
}

// ---------------------------------------------------------------------------
// Y = tanh(sum_z Part[z] + bias[col]) -> Yh/Yl (seq GEMM1 finish)
// ---------------------------------------------------------------------------
__global__ void reduce_tanh_k(const float* __restrict__ Part, int SPL, int MN4,
    const float* __restrict__ bias, int N,
    unsigned short* __restrict__ Yh, unsigned short* __restrict__ Yl)
{
  const int i = blockIdx.x * blockDim.x + threadIdx.x;
  if (i >= MN4) return;
  const size_t MN = (size_t)MN4 * 4;
  const size_t o = 4 * (size_t)i;
  f32x4 s = *(const f32x4*)(Part + o);
  for (int z = 1; z < SPL; ++z) s += *(const f32x4*)(Part + (size_t)z * MN + o);
  const int col = (int)(o % (size_t)N);
  const f32x4 b = *(const f32x4*)(bias + col);
  u16x4 hh, ll;
#pragma unroll
  for (int j = 0; j < 4; ++j) {
    const float v = fast_tanh(s[j] + b[j]);
    unsigned short h_, l_; split2(v, h_, l_);
    hh[j] = h_; ll[j] = l_;
  }
  *(u16x4*)(Yh + o) = hh;
  *(u16x4*)(Yl + o) = ll;
}

// ---------------------------------------------------------------------------
// seq GEMM2 finish: F = sum_z Part[z]; E = X + sdt*F; [Eout=E];
// v = E [+ Dv]; X = v (+ hi/lo split); [Bout=v]
// ---------------------------------------------------------------------------
__global__ void reduce_axpy_k(const float* __restrict__ part, int S, int MN4,
    const float* __restrict__ tspan,
    float* __restrict__ Xf, unsigned short* __restrict__ Xh, unsigned short* __restrict__ Xl,
    const float* __restrict__ Dv, float* __restrict__ Bout, float* __restrict__ Eout)
{
  const int i = blockIdx.x * blockDim.x + threadIdx.x;
  if (i >= MN4) return;
  const float sdt = (tspan[1] - tspan[0]) * (1.0f / 7.0f);
  const size_t MN = (size_t)MN4 * 4;
  const size_t o = 4 * (size_t)i;
  f32x4 s = *(const f32x4*)(part + o);
  for (int z = 1; z < S; ++z) s += *(const f32x4*)(part + (size_t)z * MN + o);
  f32x4 e = *(const f32x4*)(Xf + o) + sdt * s;
  if (Eout) *(f32x4*)(Eout + o) = e;
  f32x4 v = e;
  if (Dv) v += *(const f32x4*)(Dv + o);
  *(f32x4*)(Xf + o) = v;
  u16x4 hh, ll;
#pragma unroll
  for (int j = 0; j < 4; ++j) { unsigned short h_, l_; split2(v[j], h_, l_); hh[j] = h_; ll[j] = l_; }
  *(u16x4*)(Xh + o) = hh;
  *(u16x4*)(Xl + o) = ll;
  if (Bout) *(f32x4*)(Bout + o) = v;
}

// ---------------------------------------------------------------------------
__global__ void axpy_split_k(
    float* __restrict__ dstF, unsigned short* __restrict__ dstH,
    unsigned short* __restrict__ dstL,
    const float* __restrict__ A, const float* __restrict__ Fv,
    float coef, int n4)
{
  for (int i = blockIdx.x * blockDim.x + threadIdx.x; i < n4;
       i += gridDim.x * blockDim.x) {
    const size_t o = 4 * (size_t)i;
    const f32x4 a = *(const f32x4*)(A + o);
    const f32x4 f = *(const f32x4*)(Fv + o);
    f32x4 v = a + coef * f;
    *(f32x4*)(dstF + o) = v;
    if (dstH) {
      u16x4 hh, ll;
#pragma unroll
      for (int j = 0; j < 4; ++j) { unsigned short h_, l_; split2(v[j], h_, l_); hh[j] = h_; ll[j] = l_; }
      *(u16x4*)(dstH + o) = hh;
      *(u16x4*)(dstL + o) = ll;
    }
  }
}

// ---------------------------------------------------------------------------
__global__ void transpose_split_k(const float* __restrict__ W,
                                  unsigned short* __restrict__ Th,
                                  unsigned short* __restrict__ Tl,
                                  int K, int N)
{
  __shared__ float t[32][33];
  const int tx = threadIdx.x & 31, ty = threadIdx.x >> 5;
  const int n0 = blockIdx.x * 32, k0 = blockIdx.y * 32;
#pragma unroll
  for (int r = 0; r < 4; ++r) {
    const int row = ty + r * 8;
    t[row][tx] = W[(size_t)(k0 + row) * N + n0 + tx];
  }
  __syncthreads();
#pragma unroll
  for (int r = 0; r < 4; ++r) {
    const int row = ty + r * 8;
    const float v = t[tx][row];
    unsigned short hh, ll; split2(v, hh, ll);
    const size_t idx = (size_t)(n0 + row) * K + k0 + tx;
    Th[idx] = hh; Tl[idx] = ll;
  }
}

// ---------------------------------------------------------------------------
extern "C" void kernel_launch(void* const* d_in, const int* in_sizes, int n_in,
                              void* d_out, int out_size, void* d_ws, size_t ws_size,
                              hipStream_t stream)
{
  const float* Bin   = (const float*)d_in[0];
  const float* tspan = (const float*)d_in[1];
  const float* W1    = (const float*)d_in[2];
  const float* b1    = (const float*)d_in[3];
  const float* W2    = (const float*)d_in[4];

  const int n = in_sizes[1];                 // 16
  const int h = in_sizes[3];                 // 4096
  const int d = in_sizes[2] / h;             // 1024
  const int batch = in_sizes[0] / (n * d);   // 256
  const int S = 7;                           // fine_steps-1
  const int MAXIT = 2;
  const size_t NB = (size_t)batch * d;

  float* Bw = (float*)d_out;

  uint8_t* wsb = (uint8_t*)d_ws;
  size_t off = 0;
  auto carve = [&](size_t bytes) -> void* {
    off = (off + 255) & ~(size_t)255;
    void* p = wsb + off; off += bytes; return p;
  };

  const size_t WH = (size_t)d * h;
  unsigned short* W1Th = (unsigned short*)carve(WH * 2);
  unsigned short* W1Tl = (unsigned short*)carve(WH * 2);
  unsigned short* W2Th = (unsigned short*)carve(WH * 2);
  unsigned short* W2Tl = (unsigned short*)carve(WH * 2);
  float* Dbuf = (float*)carve((size_t)(n - 1) * NB * 4);
  float* Eb   = (float*)carve((size_t)n * NB * 4);

  // seq split-K partials: z=4 for GEMM1 (4 x batch x h) == z=16 for GEMM2
  // (16 x batch x d) -> same byte size
  const int SPL1 = 4, SPL2 = 16;
  float* Part = (float*)carve((size_t)SPL1 * batch * h * 4);

  const size_t per_node = (size_t)batch * ((size_t)d * 24 + (size_t)h * 4);
  int c;
  {
    size_t remb = ws_size > off + (1u << 20) ? ws_size - off - (1u << 20) : 0;
    c = (int)(remb / per_node);
    if (c < 1) c = 1;
    if (c > n - 1) c = n - 1;
  }
  const size_t CE = (size_t)c * NB;
  float*          Cst = (float*)carve(CE * 4);
  unsigned short* Csh = (unsigned short*)carve(CE * 2);
  unsigned short* Csl = (unsigned short*)carve(CE * 2);
  float*          Xf  = (float*)carve(CE * 4);
  unsigned short* Xh  = (unsigned short*)carve(CE * 2);
  unsigned short* Xl  = (unsigned short*)carve(CE * 2);
  unsigned short* XTh = (unsigned short*)carve(CE * 2);
  unsigned short* XTl = (unsigned short*)carve(CE * 2);
  float*          ACC = (float*)carve(CE * 4);
  unsigned short* Yh  = (unsigned short*)carve((size_t)c * batch * h * 2);
  unsigned short* Yl  = (unsigned short*)carve((size_t)c * batch * h * 2);

  auto ewg = [](size_t n4) -> int {
    size_t g = (n4 + 255) / 256;
    if (g > 2048) g = 2048; if (g < 1) g = 1;
    return (int)g;
  };
  auto axpy = [&](float* dF, unsigned short* dH, unsigned short* dL,
                  const float* A, const float* Fv, float coef, size_t ne) {
    const int n4 = (int)(ne / 4);
    axpy_split_k<<<ewg(n4), 256, 0, stream>>>(dF, dH, dL, A, Fv, coef, n4);
  };
  auto g1 = [&](const unsigned short* xh, const unsigned short* xl, int M) {
    gemm_k<1><<<dim3(h / 128, M / 128, 1), 256, 0, stream>>>(
        xh, xl, W1Th, W1Tl, b1, nullptr, Yh, Yl,
        nullptr, nullptr, nullptr, tspan, 0.f, 0.f, 0, M, h, d, d);
  };
  auto g2rk = [&](int M, float a1, float a2, int add) {
    gemm_k<3><<<dim3(d / 128, M / 128, 1), 256, 0, stream>>>(
        Yh, Yl, W2Th, W2Tl, nullptr, nullptr, XTh, XTl,
        Xf, ACC, nullptr, tspan, a1, a2, add, M, d, h, h);
  };
  auto g2ax = [&](int M, float* dF, unsigned short* dH, unsigned short* dL,
                  const float* Xin, float a1, float a2) {
    gemm_k<4><<<dim3(d / 128, M / 128, 1), 256, 0, stream>>>(
        Yh, Yl, W2Th, W2Tl, nullptr, nullptr, dH, dL,
        Xin, nullptr, dF, tspan, a1, a2, 0, M, d, h, h);
  };

  // ---- prep ---------------------------------------------------------------
  hipMemcpyAsync(Bw, Bin, (size_t)n * NB * 4, hipMemcpyDeviceToDevice, stream);
  transpose_split_k<<<dim3(h / 32, d / 32), 256, 0, stream>>>(W1, W1Th, W1Tl, d, h);
  transpose_split_k<<<dim3(d / 32, h / 32), 256, 0, stream>>>(W2, W2Th, W2Tl, h, d);

  const int MN4d = (int)(NB / 4);                    // batch*d/4
  const int MN4h = (int)((size_t)batch * h / 4);     // batch*h/4

  // ---- Parareal outer loop ------------------------------------------------
  for (int i = 1; i <= MAXIT + 1; ++i) {
    const int rem = n - i;

    for (int base = 0; base < rem; base += c) {
      const int cc = (rem - base) < c ? (rem - base) : c;
      const int M = cc * batch;
      const size_t ne = (size_t)M * d;
      const int j0 = i - 1 + base;
      const float* src = Bw + (size_t)j0 * NB;

      if (i == 1) {
        axpy(Cst, Csh, Csl, src, src, 0.f, ne);
        for (int s = 0; s < S; ++s) {
          g1(Csh, Csl, M);
          g2ax(M, Cst, Csh, Csl, Cst, 0.f, 1.f);
        }
      }
      axpy(Xf, Xh, Xl, src, src, 0.f, ne);
      for (int s = 0; s < S; ++s) {
        g1(Xh, Xl, M);   g2rk(M, 1.f / 6.f, 0.5f, 0);   // k1
        g1(XTh, XTl, M); g2rk(M, 1.f / 3.f, 0.5f, 1);   // k2
        g1(XTh, XTl, M); g2rk(M, 1.f / 3.f, 1.0f, 1);   // k3
        g1(XTh, XTl, M); g2ax(M, Xf, Xh, Xl, ACC, 0.f, 1.f / 6.f);  // k4
      }
      const float* Cref = (i == 1) ? Cst : (Eb + (size_t)j0 * NB);
      axpy(Dbuf + (size_t)base * NB, nullptr, nullptr, Xf, Cref, -1.f, ne);
    }

    // ---- sequential Parareal correction: full-width z-split dispatches ----
    const float* start = Bw + (size_t)(i - 1) * NB;
    axpy(Xf, Xh, Xl, start, start, 0.f, NB);
    for (int m = 0; m < rem; ++m) {
      for (int s = 0; s < S; ++s) {
        // GEMM1 partials: grid 32 x 2 x 4 = 256 WGs, 8 K-steps each
        gemm_k<2><<<dim3(h / 128, batch / 128, SPL1), 256, 0, stream>>>(
            Xh, Xl, W1Th, W1Tl, nullptr, Part, nullptr, nullptr,
            nullptr, nullptr, nullptr, tspan, 0.f, 0.f, 0, batch, h, d, d / SPL1);
        reduce_tanh_k<<<(MN4h + 255) / 256, 256, 0, stream>>>(
            Part, SPL1, MN4h, b1, h, Yh, Yl);
        // GEMM2 partials: grid 8 x 2 x 16 = 256 WGs, 8 K-steps each
        gemm_k<2><<<dim3(d / 128, batch / 128, SPL2), 256, 0, stream>>>(
            Yh, Yl, W2Th, W2Tl, nullptr, Part, nullptr, nullptr,
            nullptr, nullptr, nullptr, tspan, 0.f, 0.f, 0, batch, d, h, h / SPL2);
        const bool last = (s == S - 1);
        reduce_axpy_k<<<(MN4d + 255) / 256, 256, 0, stream>>>(
            Part, SPL2, MN4d, tspan, Xf, Xh, Xl,
            last ? Dbuf + (size_t)m * NB : nullptr,
            last ? Bw + (size_t)(i + m) * NB : nullptr,
            last ? Eb + (size_t)(i - 1 + m) * NB : nullptr);
      }
    }
  }
}